// Round 1
// baseline (382.673 us; speedup 1.0000x reference)
//
#include <hip/hip_runtime.h>
#include <hip/hip_bf16.h>

// Cabasc: B=64, S=512, Ta=8, D=768
// Pipeline:
//   memset(zero: scores, v_s, v_ts in ws; d_out)
//   k_prep        : memory_len/aspect_len + v_a
//   k_vs_mprime   : v_s = mean(memory) ; m' = bf16(memory * loc)
//   k_transpose   : W1mT[e][d] = bf16(W1_m[d][e])   (B-operand [n][k] layout)
//   k_ctx         : ctx = v_a@W1_a + v_s@W1_s + b1  (f32)
//   k_gemm_scores : MFMA bf16 128x128 tile GEMM m'@W1_m, fused tanh(.)+ctx, *w2,
//                   row-reduce -> atomicAdd scores   (h never materialized)
//   k_softmax     : alpha = softmax(scores, axis=s)
//   k_vts         : v_ts = sum_s alpha * m'  (atomic into zeroed buf)
//   k_final       : v_ms = tanh((v_ts+v_s)@Wm+bm); logits = v_ms@Wd+bd -> d_out

#define NB 64
#define NS 512
#define ND 768
#define NTA 8

typedef __attribute__((ext_vector_type(8))) __bf16 bf16x8;
typedef __attribute__((ext_vector_type(4))) float f32x4;

// ---- workspace layout (bytes) ----
#define OFF_SCORES 0u           // NB*NS f32      = 131072
#define OFF_VS 131072u          // NB*ND f32      = 196608
#define OFF_VTS 327680u         // NB*ND f32      = 196608
#define ZERO_BYTES 524288u      // [0, 524288) zero-initialized each launch
#define OFF_VA 524288u          // NB*ND f32
#define OFF_CTX 720896u         // NB*ND f32
#define OFF_ALPHA 917504u       // NB*NS f32
#define OFF_LENS 1048576u       // mlenf[64] | inv_mlen[64] | inv_alen[64]
#define OFF_W1MT 1049600u       // ND*ND bf16 = 1179648
#define OFF_MP 2229248u         // NB*NS*ND bf16 = 50331648  (total ~52.6 MB)

__device__ __forceinline__ float fast_tanh(float x) {
  x = fminf(fmaxf(x, -15.f), 15.f);
  float t = __expf(2.f * x);
  return __fdividef(t - 1.f, t + 1.f);
}

__device__ __forceinline__ unsigned bfpack2(float a, float b) {
  unsigned ua = __float_as_uint(a), ub = __float_as_uint(b);
  ua = (ua + 0x7FFFu + ((ua >> 16) & 1u)) >> 16;
  ub = (ub + 0x7FFFu + ((ub >> 16) & 1u)) >> 16;
  return ua | (ub << 16);
}

__device__ __forceinline__ unsigned short bf16b(float f) {
  unsigned u = __float_as_uint(f);
  u = (u + 0x7FFFu + ((u >> 16) & 1u)) >> 16;
  return (unsigned short)u;
}

__device__ __forceinline__ void async_copy16(const void* g, void* l) {
  __builtin_amdgcn_global_load_lds(
      (const __attribute__((address_space(1))) void*)g,
      (__attribute__((address_space(3))) void*)l, 16, 0, 0);
}

// ---------- lens + v_a ----------
__global__ __launch_bounds__(128) void k_prep(const int* __restrict__ ids,
                                              const int* __restrict__ tids,
                                              const float* __restrict__ aspect,
                                              float* __restrict__ v_a,
                                              float* __restrict__ lens) {
  int b = blockIdx.x, tid = threadIdx.x;
  __shared__ int red[128];
  __shared__ float sh_inva;
  int cnt = 0;
  for (int j = tid; j < NS; j += 128) cnt += (ids[b * NS + j] != 0);
  red[tid] = cnt;
  __syncthreads();
  for (int s = 64; s > 0; s >>= 1) {
    if (tid < s) red[tid] += red[tid + s];
    __syncthreads();
  }
  if (tid == 0) {
    int mlen = red[0];
    int acnt = 0;
    for (int t = 0; t < NTA; ++t) acnt += (tids[b * NTA + t] != 0);
    lens[b] = (float)mlen;
    lens[64 + b] = 1.0f / (float)mlen;
    float inva = 1.0f / (float)acnt;
    lens[128 + b] = inva;
    sh_inva = inva;
  }
  __syncthreads();
  float inva = sh_inva;
  for (int j = tid; j < ND; j += 128) {
    float s = 0.f;
    for (int t = 0; t < NTA; ++t) s += aspect[((size_t)b * NTA + t) * ND + j];
    v_a[b * ND + j] = s * inva;
  }
}

// ---------- v_s (mean of memory) + m' = bf16(memory * loc) ----------
__global__ __launch_bounds__(192) void k_vs_mprime(const float* __restrict__ memory,
                                                   const float* __restrict__ lens,
                                                   float* __restrict__ v_s,
                                                   unsigned short* __restrict__ mp) {
  int sc = blockIdx.x, b = blockIdx.y, tid = threadIdx.x;
  int d0 = tid * 4;
  float inv_mlen = lens[64 + b];
  float mlenf = lens[b];
  float s0 = 0, s1 = 0, s2 = 0, s3 = 0;
  for (int s = 0; s < 64; ++s) {
    int srow = sc * 64 + s;
    size_t row = (size_t)b * NS + srow;
    const float4 v = *(const float4*)(memory + row * ND + d0);
    s0 += v.x; s1 += v.y; s2 += v.z; s3 += v.w;
    float fs = (float)srow;
    float loc = (fs < mlenf) ? 1.0f - fs * inv_mlen : 1.0f;
    uint2 pk;
    pk.x = bfpack2(v.x * loc, v.y * loc);
    pk.y = bfpack2(v.z * loc, v.w * loc);
    *(uint2*)(mp + row * ND + d0) = pk;
  }
  float* p = v_s + b * ND + d0;
  atomicAdd(p + 0, s0 * inv_mlen);
  atomicAdd(p + 1, s1 * inv_mlen);
  atomicAdd(p + 2, s2 * inv_mlen);
  atomicAdd(p + 3, s3 * inv_mlen);
}

// ---------- W1mT[e][d] = bf16(W1[d][e]),  d,e in [0,768) ----------
__global__ __launch_bounds__(256) void k_transpose(const float* __restrict__ W1,
                                                   unsigned short* __restrict__ w1mt) {
  __shared__ float tile[32][33];
  int bx = blockIdx.x, by = blockIdx.y;  // bx: e-tile, by: d-tile
  int tx = threadIdx.x, ty = threadIdx.y;
  for (int j = 0; j < 32; j += 8)
    tile[ty + j][tx] = W1[(size_t)(by * 32 + ty + j) * ND + bx * 32 + tx];
  __syncthreads();
  for (int j = 0; j < 32; j += 8)
    w1mt[(size_t)(bx * 32 + ty + j) * ND + by * 32 + tx] = bf16b(tile[tx][ty + j]);
}

// ---------- ctx = v_a@W1_a + v_s@W1_s + b1 (f32) ----------
__global__ __launch_bounds__(128) void k_ctx(const float* __restrict__ W1,
                                             const float* __restrict__ b1,
                                             const float* __restrict__ v_a,
                                             const float* __restrict__ v_s,
                                             float* __restrict__ ctx) {
  int et = blockIdx.x, b = blockIdx.y, tid = threadIdx.x;
  __shared__ float va[ND], vs[ND];
  for (int j = tid; j < ND; j += 128) {
    va[j] = v_a[b * ND + j];
    vs[j] = v_s[b * ND + j];
  }
  __syncthreads();
  int e = et * 128 + tid;
  float acc = b1[e];
  const float* Wa = W1 + (size_t)ND * ND + e;
  const float* Ws = W1 + (size_t)2 * ND * ND + e;
#pragma unroll 8
  for (int d = 0; d < ND; ++d) {
    acc += va[d] * Wa[(size_t)d * ND];
    acc += vs[d] * Ws[(size_t)d * ND];
  }
  ctx[b * ND + e] = acc;
}

// ---------- big GEMM: scores[row] = sum_e tanh((m'@W1_m)[row,e] + ctx) * w2[e] ----------
// 128x128 tile, 4 waves (2x2 of 64x64), 16x16x32 bf16 MFMA, BK=32, global_load_lds w=16.
// LDS chunk swizzle q_phys = q ^ ((m>>1)&3) applied on the global source side
// (dest of global_load_lds is wave-uniform base + lane*16) -> 2-way max bank aliasing.
__global__ __launch_bounds__(256) void k_gemm_scores(const unsigned short* __restrict__ mp,
                                                     const unsigned short* __restrict__ w1mt,
                                                     const float* __restrict__ ctx,
                                                     const float* __restrict__ w2,
                                                     float* __restrict__ scores) {
  __shared__ char lds[16384];
  char* ldsA = lds;
  char* ldsB = lds + 8192;
  const int tid = threadIdx.x;
  const int wave = tid >> 6, lane = tid & 63;
  const int rt = blockIdx.x, et = blockIdx.y;
  const int row0 = rt * 128, n0 = et * 128;
  const int b = row0 >> 9;  // 128 | 512 so a tile never crosses a batch
  const int wm = wave & 1, wn = wave >> 1;
  // staging lane mapping: 16 rows per issue, 4 lanes/row, swizzled chunk from global
  const int sm = lane >> 2;
  const int sq = (lane & 3) ^ ((sm >> 1) & 3);
  const char* Abase = (const char*)mp + ((size_t)(row0 + sm) * ND) * 2 + sq * 16;
  const char* Bbase = (const char*)w1mt + ((size_t)(n0 + sm) * ND) * 2 + sq * 16;

  f32x4 acc[4][4];
#pragma unroll
  for (int i = 0; i < 4; ++i)
#pragma unroll
    for (int t = 0; t < 4; ++t) acc[i][t] = (f32x4){0.f, 0.f, 0.f, 0.f};

  const int q = lane >> 4, c = lane & 15;
  int offA[4], offB[4];
#pragma unroll
  for (int i = 0; i < 4; ++i) {
    int ml = wm * 64 + i * 16 + c;
    offA[i] = (ml >> 4) * 1024 + (ml & 15) * 64 + ((q ^ (((ml & 15) >> 1) & 3)) * 16);
    int nl = wn * 64 + i * 16 + c;
    offB[i] = (nl >> 4) * 1024 + (nl & 15) * 64 + ((q ^ (((nl & 15) >> 1) & 3)) * 16);
  }

  for (int k0 = 0; k0 < ND; k0 += 32) {
#pragma unroll
    for (int i = 0; i < 2; ++i) {
      int g = wave * 2 + i;
      async_copy16(Abase + (size_t)g * 16 * (ND * 2) + k0 * 2, ldsA + g * 1024);
      async_copy16(Bbase + (size_t)g * 16 * (ND * 2) + k0 * 2, ldsB + g * 1024);
    }
    __syncthreads();  // drains vmcnt before barrier (compiler-inserted)
    bf16x8 af[4], bfr[4];
#pragma unroll
    for (int i = 0; i < 4; ++i) {
      af[i] = *(const bf16x8*)(ldsA + offA[i]);
      bfr[i] = *(const bf16x8*)(ldsB + offB[i]);
    }
#pragma unroll
    for (int i = 0; i < 4; ++i)
#pragma unroll
      for (int t = 0; t < 4; ++t)
        acc[i][t] = __builtin_amdgcn_mfma_f32_16x16x32_bf16(af[i], bfr[t], acc[i][t], 0, 0, 0);
    __syncthreads();
  }

  // epilogue: C/D layout row = q*4+r, col = c  (within each 16x16 tile)
  float ctxv[4], w2v[4];
#pragma unroll
  for (int t = 0; t < 4; ++t) {
    int n = n0 + wn * 64 + t * 16 + c;
    ctxv[t] = ctx[b * ND + n];
    w2v[t] = w2[n];
  }
#pragma unroll
  for (int i = 0; i < 4; ++i) {
#pragma unroll
    for (int r = 0; r < 4; ++r) {
      float s = 0.f;
#pragma unroll
      for (int t = 0; t < 4; ++t) s += fast_tanh(acc[i][t][r] + ctxv[t]) * w2v[t];
      s += __shfl_xor(s, 1, 64);
      s += __shfl_xor(s, 2, 64);
      s += __shfl_xor(s, 4, 64);
      s += __shfl_xor(s, 8, 64);
      if (c == 0) atomicAdd(&scores[row0 + wm * 64 + i * 16 + q * 4 + r], s);
    }
  }
}

// ---------- softmax over s ----------
__global__ __launch_bounds__(512) void k_softmax(const float* __restrict__ scores,
                                                 float* __restrict__ alpha) {
  int b = blockIdx.x, tid = threadIdx.x;
  int wid = tid >> 6, lane = tid & 63;
  __shared__ float red[8], red2[8];
  float v = scores[b * NS + tid];
  float m = v;
  for (int off = 1; off < 64; off <<= 1) m = fmaxf(m, __shfl_xor(m, off, 64));
  if (lane == 0) red[wid] = m;
  __syncthreads();
  if (tid == 0) {
    float mm = red[0];
    for (int i = 1; i < 8; ++i) mm = fmaxf(mm, red[i]);
    red[0] = mm;
  }
  __syncthreads();
  float M = red[0];
  float e = __expf(v - M);
  float s = e;
  for (int off = 1; off < 64; off <<= 1) s += __shfl_xor(s, off, 64);
  if (lane == 0) red2[wid] = s;
  __syncthreads();
  if (tid == 0) {
    float ss = 0.f;
    for (int i = 0; i < 8; ++i) ss += red2[i];
    red2[0] = ss;
  }
  __syncthreads();
  alpha[b * NS + tid] = e / red2[0];
}

// ---------- v_ts = sum_s alpha * m' ----------
__global__ __launch_bounds__(192) void k_vts(const unsigned short* __restrict__ mp,
                                             const float* __restrict__ alpha,
                                             float* __restrict__ v_ts) {
  int sc = blockIdx.x, b = blockIdx.y, tid = threadIdx.x;
  __shared__ float al[64];
  if (tid < 64) al[tid] = alpha[b * NS + sc * 64 + tid];
  __syncthreads();
  int d0 = tid * 4;
  float a0 = 0, a1 = 0, a2 = 0, a3 = 0;
  for (int s = 0; s < 64; ++s) {
    size_t row = (size_t)b * NS + sc * 64 + s;
    uint2 pk = *(const uint2*)(mp + row * ND + d0);
    float a = al[s];
    a0 += a * __uint_as_float(pk.x << 16);
    a1 += a * __uint_as_float(pk.x & 0xFFFF0000u);
    a2 += a * __uint_as_float(pk.y << 16);
    a3 += a * __uint_as_float(pk.y & 0xFFFF0000u);
  }
  float* p = v_ts + b * ND + d0;
  atomicAdd(p + 0, a0);
  atomicAdd(p + 1, a1);
  atomicAdd(p + 2, a2);
  atomicAdd(p + 3, a3);
}

// ---------- v_ms = tanh((v_ts+v_s)@Wm + bm); logits = v_ms@Wd + bd ----------
__global__ __launch_bounds__(128) void k_final(const float* __restrict__ v_ts,
                                               const float* __restrict__ v_s,
                                               const float* __restrict__ Wm,
                                               const float* __restrict__ bm,
                                               const float* __restrict__ Wd,
                                               const float* __restrict__ bd,
                                               float* __restrict__ out) {
  int et = blockIdx.x, b = blockIdx.y, tid = threadIdx.x;
  __shared__ float vns[ND];
  __shared__ float red[2][3];
  for (int j = tid; j < ND; j += 128) vns[j] = v_ts[b * ND + j] + v_s[b * ND + j];
  __syncthreads();
  int e = et * 128 + tid;
  float acc = bm[e];
#pragma unroll 8
  for (int d = 0; d < ND; ++d) acc += vns[d] * Wm[(size_t)d * ND + e];
  float vm = fast_tanh(acc);
  float p0 = vm * Wd[e * 3 + 0];
  float p1 = vm * Wd[e * 3 + 1];
  float p2 = vm * Wd[e * 3 + 2];
  for (int off = 1; off < 64; off <<= 1) {
    p0 += __shfl_xor(p0, off, 64);
    p1 += __shfl_xor(p1, off, 64);
    p2 += __shfl_xor(p2, off, 64);
  }
  int wid = tid >> 6, lane = tid & 63;
  if (lane == 0) { red[wid][0] = p0; red[wid][1] = p1; red[wid][2] = p2; }
  __syncthreads();
  if (tid == 0) {
    atomicAdd(&out[b * 3 + 0], red[0][0] + red[1][0]);
    atomicAdd(&out[b * 3 + 1], red[0][1] + red[1][1]);
    atomicAdd(&out[b * 3 + 2], red[0][2] + red[1][2]);
  }
  if (et == 0 && tid < 3) atomicAdd(&out[b * 3 + tid], bd[tid]);
}

extern "C" void kernel_launch(void* const* d_in, const int* in_sizes, int n_in,
                              void* d_out, int out_size, void* d_ws, size_t ws_size,
                              hipStream_t stream) {
  const float* memory = (const float*)d_in[0];
  const float* aspect = (const float*)d_in[1];
  const int* ids = (const int*)d_in[2];
  const int* tids = (const int*)d_in[3];
  const float* W1 = (const float*)d_in[4];
  const float* b1 = (const float*)d_in[5];
  const float* w2 = (const float*)d_in[6];
  const float* Wm = (const float*)d_in[7];
  const float* bm = (const float*)d_in[8];
  const float* Wd = (const float*)d_in[9];
  const float* bd = (const float*)d_in[10];
  float* out = (float*)d_out;

  char* ws = (char*)d_ws;
  float* scores = (float*)(ws + OFF_SCORES);
  float* v_s = (float*)(ws + OFF_VS);
  float* v_ts = (float*)(ws + OFF_VTS);
  float* v_a = (float*)(ws + OFF_VA);
  float* ctx = (float*)(ws + OFF_CTX);
  float* alpha = (float*)(ws + OFF_ALPHA);
  float* lens = (float*)(ws + OFF_LENS);
  unsigned short* w1mt = (unsigned short*)(ws + OFF_W1MT);
  unsigned short* mp = (unsigned short*)(ws + OFF_MP);

  hipMemsetAsync(ws, 0, ZERO_BYTES, stream);
  hipMemsetAsync(d_out, 0, (size_t)out_size * sizeof(float), stream);

  k_prep<<<NB, 128, 0, stream>>>(ids, tids, aspect, v_a, lens);
  k_vs_mprime<<<dim3(8, NB), 192, 0, stream>>>(memory, lens, v_s, mp);
  k_transpose<<<dim3(24, 24), dim3(32, 8), 0, stream>>>(W1, w1mt);
  k_ctx<<<dim3(6, NB), 128, 0, stream>>>(W1, b1, v_a, v_s, ctx);
  k_gemm_scores<<<dim3(256, 6), 256, 0, stream>>>(mp, w1mt, ctx, w2, scores);
  k_softmax<<<NB, 512, 0, stream>>>(scores, alpha);
  k_vts<<<dim3(8, NB), 192, 0, stream>>>(mp, alpha, v_ts);
  k_final<<<dim3(6, NB), 128, 0, stream>>>(v_ts, v_s, Wm, bm, Wd, bd, out);
}

// Round 2
// 323.377 us; speedup vs baseline: 1.1834x; 1.1834x over previous
//
#include <hip/hip_runtime.h>
#include <hip/hip_bf16.h>

// Cabasc: B=64, S=512, Ta=8, D=768
// Round 2: GEMM BK=64 (m97 structure, halved barriers), split-K ctx/final GEMVs.

#define NB 64
#define NS 512
#define ND 768
#define NTA 8

typedef __attribute__((ext_vector_type(8))) __bf16 bf16x8;
typedef __attribute__((ext_vector_type(4))) float f32x4;

// ---- workspace layout (bytes) ----
#define OFF_SCORES 0u           // NB*NS f32   = 131072
#define OFF_VS 131072u          // NB*ND f32   = 196608
#define OFF_VTS 327680u         // NB*ND f32
#define OFF_CTX 524288u         // NB*ND f32   (accumulated via atomics)
#define OFF_U 720896u           // NB*ND f32   (pre-tanh v_ms accumulator)
#define ZERO_BYTES 917504u      // [0, 917504) zero-initialized each launch
#define OFF_VA 917504u          // NB*ND f32
#define OFF_ALPHA 1114112u     // NB*NS f32
#define OFF_LENS 1245184u      // mlenf[64] | inv_mlen[64] | inv_alen[64]
#define OFF_W1MT 1246208u      // ND*ND bf16 = 1179648
#define OFF_MP 2425856u        // NB*NS*ND bf16 = 50331648 (total ~52.8 MB)

__device__ __forceinline__ float fast_tanh(float x) {
  x = fminf(fmaxf(x, -15.f), 15.f);
  float t = __expf(2.f * x);
  return __fdividef(t - 1.f, t + 1.f);
}

__device__ __forceinline__ unsigned bfpack2(float a, float b) {
  unsigned ua = __float_as_uint(a), ub = __float_as_uint(b);
  ua = (ua + 0x7FFFu + ((ua >> 16) & 1u)) >> 16;
  ub = (ub + 0x7FFFu + ((ub >> 16) & 1u)) >> 16;
  return ua | (ub << 16);
}

__device__ __forceinline__ unsigned short bf16b(float f) {
  unsigned u = __float_as_uint(f);
  u = (u + 0x7FFFu + ((u >> 16) & 1u)) >> 16;
  return (unsigned short)u;
}

__device__ __forceinline__ void async_copy16(const void* g, void* l) {
  __builtin_amdgcn_global_load_lds(
      (const __attribute__((address_space(1))) void*)g,
      (__attribute__((address_space(3))) void*)l, 16, 0, 0);
}

// ---------- lens + v_a ----------
__global__ __launch_bounds__(128) void k_prep(const int* __restrict__ ids,
                                              const int* __restrict__ tids,
                                              const float* __restrict__ aspect,
                                              float* __restrict__ v_a,
                                              float* __restrict__ lens) {
  int b = blockIdx.x, tid = threadIdx.x;
  __shared__ int red[128];
  __shared__ float sh_inva;
  int cnt = 0;
  for (int j = tid; j < NS; j += 128) cnt += (ids[b * NS + j] != 0);
  red[tid] = cnt;
  __syncthreads();
  for (int s = 64; s > 0; s >>= 1) {
    if (tid < s) red[tid] += red[tid + s];
    __syncthreads();
  }
  if (tid == 0) {
    int mlen = red[0];
    int acnt = 0;
    for (int t = 0; t < NTA; ++t) acnt += (tids[b * NTA + t] != 0);
    lens[b] = (float)mlen;
    lens[64 + b] = 1.0f / (float)mlen;
    float inva = 1.0f / (float)acnt;
    lens[128 + b] = inva;
    sh_inva = inva;
  }
  __syncthreads();
  float inva = sh_inva;
  for (int j = tid; j < ND; j += 128) {
    float s = 0.f;
    for (int t = 0; t < NTA; ++t) s += aspect[((size_t)b * NTA + t) * ND + j];
    v_a[b * ND + j] = s * inva;
  }
}

// ---------- v_s (mean of memory) + m' = bf16(memory * loc) ----------
__global__ __launch_bounds__(192) void k_vs_mprime(const float* __restrict__ memory,
                                                   const float* __restrict__ lens,
                                                   float* __restrict__ v_s,
                                                   unsigned short* __restrict__ mp) {
  int sc = blockIdx.x, b = blockIdx.y, tid = threadIdx.x;
  int d0 = tid * 4;
  float inv_mlen = lens[64 + b];
  float mlenf = lens[b];
  float s0 = 0, s1 = 0, s2 = 0, s3 = 0;
  for (int s = 0; s < 64; ++s) {
    int srow = sc * 64 + s;
    size_t row = (size_t)b * NS + srow;
    const float4 v = *(const float4*)(memory + row * ND + d0);
    s0 += v.x; s1 += v.y; s2 += v.z; s3 += v.w;
    float fs = (float)srow;
    float loc = (fs < mlenf) ? 1.0f - fs * inv_mlen : 1.0f;
    uint2 pk;
    pk.x = bfpack2(v.x * loc, v.y * loc);
    pk.y = bfpack2(v.z * loc, v.w * loc);
    *(uint2*)(mp + row * ND + d0) = pk;
  }
  float* p = v_s + b * ND + d0;
  atomicAdd(p + 0, s0 * inv_mlen);
  atomicAdd(p + 1, s1 * inv_mlen);
  atomicAdd(p + 2, s2 * inv_mlen);
  atomicAdd(p + 3, s3 * inv_mlen);
}

// ---------- W1mT[e][d] = bf16(W1[d][e]) ----------
__global__ __launch_bounds__(256) void k_transpose(const float* __restrict__ W1,
                                                   unsigned short* __restrict__ w1mt) {
  __shared__ float tile[32][33];
  int bx = blockIdx.x, by = blockIdx.y;
  int tx = threadIdx.x, ty = threadIdx.y;
  for (int j = 0; j < 32; j += 8)
    tile[ty + j][tx] = W1[(size_t)(by * 32 + ty + j) * ND + bx * 32 + tx];
  __syncthreads();
  for (int j = 0; j < 32; j += 8)
    w1mt[(size_t)(bx * 32 + ty + j) * ND + by * 32 + tx] = bf16b(tile[tx][ty + j]);
}

// ---------- ctx += partial( [v_a;v_s] @ [W1_a;W1_s] ), split-K over 4 chunks ----------
__global__ __launch_bounds__(128) void k_ctx(const float* __restrict__ W1,
                                             const float* __restrict__ v_a,
                                             const float* __restrict__ v_s,
                                             float* __restrict__ ctx) {
  int et = blockIdx.x, b = blockIdx.y, dc = blockIdx.z, tid = threadIdx.x;
  __shared__ float vbuf[384];
  for (int j = tid; j < 384; j += 128) {
    int k = dc * 384 + j;
    vbuf[j] = (k < ND) ? v_a[b * ND + k] : v_s[b * ND + (k - ND)];
  }
  __syncthreads();
  int e = et * 128 + tid;
  float acc = 0.f;
  const float* Wk = W1 + (size_t)(ND + dc * 384) * ND + e;  // rows 768.. of W1 = [W1_a; W1_s]
#pragma unroll 8
  for (int j = 0; j < 384; ++j) acc += vbuf[j] * Wk[(size_t)j * ND];
  atomicAdd(&ctx[b * ND + e], acc);
}

// ---------- big GEMM: scores[row] += sum_e tanh((m'@W1_m)[row,e]+ctx+b1)*w2[e] ----------
// 128x128 tile, BK=64, 4 waves (2x2), 16x16x32 bf16 MFMA, global_load_lds w=16.
// LDS row = 64 k = 128 B = 32 banks; chunk swizzle phys_q = q ^ (row&7) (applied on
// the global source side; dest of global_load_lds is base+lane*16). Per-8-lane phase
// all banks distinct -> conflict-free (round-1 measured 0 with same scheme).
__global__ __launch_bounds__(256) void k_gemm_scores(const unsigned short* __restrict__ mp,
                                                     const unsigned short* __restrict__ w1mt,
                                                     const float* __restrict__ ctx,
                                                     const float* __restrict__ b1,
                                                     const float* __restrict__ w2,
                                                     float* __restrict__ scores) {
  __shared__ char lds[32768];
  char* ldsA = lds;
  char* ldsB = lds + 16384;
  const int tid = threadIdx.x;
  const int wave = tid >> 6, lane = tid & 63;
  const int rt = blockIdx.x, et = blockIdx.y;
  const int row0 = rt * 128, n0 = et * 128;
  const int b = row0 >> 9;  // 128 | 512: tile never crosses a batch
  const int wm = wave & 1, wn = wave >> 1;

  // staging: each issue = 64 lanes x 16B = 8 rows x 8 chunks
  const int lrow = lane >> 3;                 // 0..7 row within issue
  const int qlog = (lane & 7) ^ lrow;         // logical chunk for this phys slot
  const char* Abase = (const char*)mp + (size_t)(row0 + lrow) * (ND * 2) + qlog * 16;
  const char* Bbase = (const char*)w1mt + (size_t)(n0 + lrow) * (ND * 2) + qlog * 16;

  f32x4 acc[4][4];
#pragma unroll
  for (int i = 0; i < 4; ++i)
#pragma unroll
    for (int t = 0; t < 4; ++t) acc[i][t] = (f32x4){0.f, 0.f, 0.f, 0.f};

  const int q2 = lane >> 4, c = lane & 15;
  int offA[4][2], offB[4][2];
#pragma unroll
  for (int i = 0; i < 4; ++i) {
    int ml = wm * 64 + i * 16 + c;
    offA[i][0] = ml * 128 + ((q2 ^ (ml & 7)) * 16);
    offA[i][1] = ml * 128 + (((4 + q2) ^ (ml & 7)) * 16);
    int nl = wn * 64 + i * 16 + c;
    offB[i][0] = nl * 128 + ((q2 ^ (nl & 7)) * 16);
    offB[i][1] = nl * 128 + (((4 + q2) ^ (nl & 7)) * 16);
  }

  for (int kb = 0; kb < ND * 2; kb += 128) {  // 12 K-steps of 64 k (128 B/row)
#pragma unroll
    for (int i = 0; i < 4; ++i) {
      int g = wave * 4 + i;
      async_copy16(Abase + (size_t)g * 8 * (ND * 2) + kb, ldsA + g * 1024);
      async_copy16(Bbase + (size_t)g * 8 * (ND * 2) + kb, ldsB + g * 1024);
    }
    __syncthreads();
    bf16x8 af[2][4], bfr[2][4];
#pragma unroll
    for (int kk = 0; kk < 2; ++kk)
#pragma unroll
      for (int i = 0; i < 4; ++i) {
        af[kk][i] = *(const bf16x8*)(ldsA + offA[i][kk]);
        bfr[kk][i] = *(const bf16x8*)(ldsB + offB[i][kk]);
      }
#pragma unroll
    for (int kk = 0; kk < 2; ++kk)
#pragma unroll
      for (int i = 0; i < 4; ++i)
#pragma unroll
        for (int t = 0; t < 4; ++t)
          acc[i][t] = __builtin_amdgcn_mfma_f32_16x16x32_bf16(af[kk][i], bfr[kk][t], acc[i][t], 0, 0, 0);
    __syncthreads();
  }

  // epilogue: C/D layout row = q2*4+r, col = c
  float ctxv[4], w2v[4];
#pragma unroll
  for (int t = 0; t < 4; ++t) {
    int n = n0 + wn * 64 + t * 16 + c;
    ctxv[t] = ctx[b * ND + n] + b1[n];
    w2v[t] = w2[n];
  }
#pragma unroll
  for (int i = 0; i < 4; ++i) {
#pragma unroll
    for (int r = 0; r < 4; ++r) {
      float s = 0.f;
#pragma unroll
      for (int t = 0; t < 4; ++t) s += fast_tanh(acc[i][t][r] + ctxv[t]) * w2v[t];
      s += __shfl_xor(s, 1, 64);
      s += __shfl_xor(s, 2, 64);
      s += __shfl_xor(s, 4, 64);
      s += __shfl_xor(s, 8, 64);
      if (c == 0) atomicAdd(&scores[row0 + wm * 64 + i * 16 + q2 * 4 + r], s);
    }
  }
}

// ---------- softmax over s ----------
__global__ __launch_bounds__(512) void k_softmax(const float* __restrict__ scores,
                                                 float* __restrict__ alpha) {
  int b = blockIdx.x, tid = threadIdx.x;
  int wid = tid >> 6, lane = tid & 63;
  __shared__ float red[8], red2[8];
  float v = scores[b * NS + tid];
  float m = v;
  for (int off = 1; off < 64; off <<= 1) m = fmaxf(m, __shfl_xor(m, off, 64));
  if (lane == 0) red[wid] = m;
  __syncthreads();
  if (tid == 0) {
    float mm = red[0];
    for (int i = 1; i < 8; ++i) mm = fmaxf(mm, red[i]);
    red[0] = mm;
  }
  __syncthreads();
  float M = red[0];
  float e = __expf(v - M);
  float s = e;
  for (int off = 1; off < 64; off <<= 1) s += __shfl_xor(s, off, 64);
  if (lane == 0) red2[wid] = s;
  __syncthreads();
  if (tid == 0) {
    float ss = 0.f;
    for (int i = 0; i < 8; ++i) ss += red2[i];
    red2[0] = ss;
  }
  __syncthreads();
  alpha[b * NS + tid] = e / red2[0];
}

// ---------- v_ts = sum_s alpha * m' ----------
__global__ __launch_bounds__(192) void k_vts(const unsigned short* __restrict__ mp,
                                             const float* __restrict__ alpha,
                                             float* __restrict__ v_ts) {
  int sc = blockIdx.x, b = blockIdx.y, tid = threadIdx.x;
  __shared__ float al[64];
  if (tid < 64) al[tid] = alpha[b * NS + sc * 64 + tid];
  __syncthreads();
  int d0 = tid * 4;
  float a0 = 0, a1 = 0, a2 = 0, a3 = 0;
  for (int s = 0; s < 64; ++s) {
    size_t row = (size_t)b * NS + sc * 64 + s;
    uint2 pk = *(const uint2*)(mp + row * ND + d0);
    float a = al[s];
    a0 += a * __uint_as_float(pk.x << 16);
    a1 += a * __uint_as_float(pk.x & 0xFFFF0000u);
    a2 += a * __uint_as_float(pk.y << 16);
    a3 += a * __uint_as_float(pk.y & 0xFFFF0000u);
  }
  float* p = v_ts + b * ND + d0;
  atomicAdd(p + 0, a0);
  atomicAdd(p + 1, a1);
  atomicAdd(p + 2, a2);
  atomicAdd(p + 3, a3);
}

// ---------- u += partial( (v_ts+v_s) @ Wm ), split-K over 4 chunks ----------
__global__ __launch_bounds__(128) void k_final1(const float* __restrict__ v_ts,
                                                const float* __restrict__ v_s,
                                                const float* __restrict__ Wm,
                                                float* __restrict__ u) {
  int et = blockIdx.x, b = blockIdx.y, dc = blockIdx.z, tid = threadIdx.x;
  __shared__ float vbuf[192];
  for (int j = tid; j < 192; j += 128) {
    int d = dc * 192 + j;
    vbuf[j] = v_ts[b * ND + d] + v_s[b * ND + d];
  }
  __syncthreads();
  int e = et * 128 + tid;
  float acc = 0.f;
  const float* Wk = Wm + (size_t)(dc * 192) * ND + e;
#pragma unroll 8
  for (int j = 0; j < 192; ++j) acc += vbuf[j] * Wk[(size_t)j * ND];
  atomicAdd(&u[b * ND + e], acc);
}

// ---------- logits = tanh(u+bm) @ Wd + bd ----------
__global__ __launch_bounds__(256) void k_final2(const float* __restrict__ u,
                                                const float* __restrict__ bm,
                                                const float* __restrict__ Wd,
                                                const float* __restrict__ bd,
                                                float* __restrict__ out) {
  int b = blockIdx.x, tid = threadIdx.x;
  int wid = tid >> 6, lane = tid & 63;
  __shared__ float red[4][3];
  float p0 = 0, p1 = 0, p2 = 0;
  for (int e = tid; e < ND; e += 256) {
    float vm = fast_tanh(u[b * ND + e] + bm[e]);
    p0 += vm * Wd[e * 3 + 0];
    p1 += vm * Wd[e * 3 + 1];
    p2 += vm * Wd[e * 3 + 2];
  }
  for (int off = 1; off < 64; off <<= 1) {
    p0 += __shfl_xor(p0, off, 64);
    p1 += __shfl_xor(p1, off, 64);
    p2 += __shfl_xor(p2, off, 64);
  }
  if (lane == 0) { red[wid][0] = p0; red[wid][1] = p1; red[wid][2] = p2; }
  __syncthreads();
  if (tid == 0) {
    out[b * 3 + 0] = red[0][0] + red[1][0] + red[2][0] + red[3][0] + bd[0];
    out[b * 3 + 1] = red[0][1] + red[1][1] + red[2][1] + red[3][1] + bd[1];
    out[b * 3 + 2] = red[0][2] + red[1][2] + red[2][2] + red[3][2] + bd[2];
  }
}

extern "C" void kernel_launch(void* const* d_in, const int* in_sizes, int n_in,
                              void* d_out, int out_size, void* d_ws, size_t ws_size,
                              hipStream_t stream) {
  const float* memory = (const float*)d_in[0];
  const float* aspect = (const float*)d_in[1];
  const int* ids = (const int*)d_in[2];
  const int* tids = (const int*)d_in[3];
  const float* W1 = (const float*)d_in[4];
  const float* b1 = (const float*)d_in[5];
  const float* w2 = (const float*)d_in[6];
  const float* Wm = (const float*)d_in[7];
  const float* bm = (const float*)d_in[8];
  const float* Wd = (const float*)d_in[9];
  const float* bd = (const float*)d_in[10];
  float* out = (float*)d_out;

  char* ws = (char*)d_ws;
  float* scores = (float*)(ws + OFF_SCORES);
  float* v_s = (float*)(ws + OFF_VS);
  float* v_ts = (float*)(ws + OFF_VTS);
  float* ctx = (float*)(ws + OFF_CTX);
  float* u = (float*)(ws + OFF_U);
  float* v_a = (float*)(ws + OFF_VA);
  float* alpha = (float*)(ws + OFF_ALPHA);
  float* lens = (float*)(ws + OFF_LENS);
  unsigned short* w1mt = (unsigned short*)(ws + OFF_W1MT);
  unsigned short* mp = (unsigned short*)(ws + OFF_MP);

  hipMemsetAsync(ws, 0, ZERO_BYTES, stream);

  k_prep<<<NB, 128, 0, stream>>>(ids, tids, aspect, v_a, lens);
  k_transpose<<<dim3(24, 24), dim3(32, 8), 0, stream>>>(W1, w1mt);
  k_vs_mprime<<<dim3(8, NB), 192, 0, stream>>>(memory, lens, v_s, mp);
  k_ctx<<<dim3(6, NB, 4), 128, 0, stream>>>(W1, v_a, v_s, ctx);
  k_gemm_scores<<<dim3(256, 6), 256, 0, stream>>>(mp, w1mt, ctx, b1, w2, scores);
  k_softmax<<<NB, 512, 0, stream>>>(scores, alpha);
  k_vts<<<dim3(8, NB), 192, 0, stream>>>(mp, alpha, v_ts);
  k_final1<<<dim3(6, NB, 4), 128, 0, stream>>>(v_ts, v_s, Wm, u);
  k_final2<<<NB, 256, 0, stream>>>(u, bm, Wd, bd, out);
}